// Round 6
// baseline (515.463 us; speedup 1.0000x reference)
//
#include <hip/hip_runtime.h>
#include <hip/hip_bf16.h>
#include <stdint.h>

#define E_NUM 16
#define T_NUM 8192
#define H_DIM 1024
#define I_DIM 4096
#define MPE   512   // tokens per expert

typedef __attribute__((ext_vector_type(8))) short short8;
typedef __attribute__((ext_vector_type(4))) float f32x4;
using bf16 = __hip_bfloat16;

typedef const __attribute__((address_space(1))) void GLV;
typedef __attribute__((address_space(3))) void LDSV;

__device__ __forceinline__ uint32_t pack2_bf16(float a, float b) {
  union { float f; uint32_t u; } ua, ub;
  ua.f = a; ub.f = b;
  uint32_t x = ua.u + (0x7FFFu + ((ua.u >> 16) & 1u));
  uint32_t y = ub.u + (0x7FFFu + ((ub.u >> 16) & 1u));
  return (x >> 16) | (y & 0xFFFF0000u);
}

// 8 f32 (two float4) -> uint4 of 8 bf16 (RNE, v_cvt_pk_bf16_f32)
__device__ __forceinline__ uint4 cvt8u(float4 a, float4 b) {
  union { uint4 u; __hip_bfloat162 h[4]; } r;
  r.h[0] = __float22bfloat162_rn({a.x, a.y});
  r.h[1] = __float22bfloat162_rn({a.z, a.w});
  r.h[2] = __float22bfloat162_rn({b.x, b.y});
  r.h[3] = __float22bfloat162_rn({b.z, b.w});
  return r.u;
}

// ---------------- gather + cast: xp[r] = bf16(hs[perm[r]]) ----------------
__global__ __launch_bounds__(256)
void gather_cast_kernel(const float* __restrict__ hs, const int* __restrict__ perm,
                        uint32_t* __restrict__ xp) {
  const int r = blockIdx.x;
  const int t = threadIdx.x;
  const int src = perm[r];
  float4 v = ((const float4*)(hs + (size_t)src * H_DIM))[t];
  uint2 o;
  o.x = pack2_bf16(v.x, v.y);
  o.y = pack2_bf16(v.z, v.w);
  ((uint2*)(xp + (size_t)r * (H_DIM / 2)))[t] = o;
}

// ---------------- grouped GEMM, m201-style 4-phase/K-tile pipeline ----------
// C = A(bf16,[E][512][K]) * B(f32,[E][N][K])^T.  BM=256, BN in {256,128}, BK=64.
// 512 thr = 8 waves (2M x 4N); per-wave 128 x (BN/4); acc 8 x NREP f32x4.
// LDS (all layouts/swizzles bit-identical to R4's measured-0-conflict ones):
//   A: [256][64] bf16 dbuf, global_load_lds w/ pre-swizzled source chunk^(row&7)
//   B: [BN][64] bf16 dbuf, reg-staged fp32 -> cvt_pk -> XOR-swizzled ds_write
// Per K-tile t, 4 phases, each {ds ops | bar | lgkm0 | setprio MFMA | bar}:
//  p0: issue A(t+1) glds; vmcnt(4) [B(t+1) regs landed, A(t+1) flying];
//      cvt+ds_write B(t+1); read a[0..3]k0 + b[*]k0;   MFMA m0-3 k0
//  p1: read a[0..3]k1 + b[*]k1; issue B(t+2)->regs;    MFMA m0-3 k1
//  p2: read a[4..7]k0;                                 MFMA m4-7 k0
//  p3: read a[4..7]k1; vmcnt(2*NREP) [A(t+1) landed, B(t+2) flying];
//                                                      MFMA m4-7 k1
template<bool EPI1, int BN, int N, int K, int LOG_NBN>
__global__ __launch_bounds__(512, 2)
void moe_gemm_kernel(const bf16* __restrict__ A, const float* __restrict__ Bw,
                     const float* __restrict__ bias, bf16* __restrict__ Hout,
                     float* __restrict__ Oout, const int* __restrict__ perm) {
  constexpr int NREP = BN / 64;      // 4 (GEMM1) or 2 (GEMM2)
  constexpr int NK   = K / 64;
  __shared__ bf16 As[2][256 * 64];   // 32 KB each
  __shared__ bf16 Bs[2][BN * 64];    // 32/16 KB each

  // bijective chunked XCD swizzle (m204); nwg % 8 == 0
  const int nwg = gridDim.x, qx = nwg >> 3, orig = blockIdx.x;
  const int wg = (orig & 7) * qx + (orig >> 3);
  const int bm = wg & 1;
  const int bn = (wg >> 1) & ((1 << LOG_NBN) - 1);
  const int e  = wg >> (1 + LOG_NBN);

  const int tid = threadIdx.x;
  const int l = tid & 63;
  const int w = tid >> 6;
  const int wr = w >> 2, wc = w & 3;       // 2 M-waves x 4 N-waves
  const int fr = l & 15, fq = l >> 4;
  const int rx = fr & 7;

  const bf16*  Ae = A  + ((size_t)e * MPE + (size_t)bm * 256) * K;
  const float* Be = Bw + ((size_t)e * N + (size_t)bn * BN) * K;

  // A staging (R4-validated): glds set i covers rows i*64 + (tid>>3)
  const int ar = tid >> 3;
  const bf16* Asrc = Ae + (size_t)ar * K + (((tid & 7) ^ (ar & 7)) << 3);

  // B staging: row bwrow, starting chunk bwc (chunk = 8 elems)
  const int bwrow = (NREP == 4) ? (tid >> 1) : (tid >> 2);
  const int bwc   = (NREP == 4) ? ((tid & 1) << 2) : ((tid & 3) << 1);
  const float* Bsrc = Be + (size_t)bwrow * K + bwc * 8;

  // fragment read offsets
  const int aro = (wr * 128 + fr) * 64;              // + m*1024 + chunk*8
  const int bro = (wc * (BN / 4) + fr) * 64;         // + n*1024 + chunk*8
  const int ch0 = ((0 * 4 + fq) ^ rx) << 3;          // kstep 0
  const int ch1 = ((1 * 4 + fq) ^ rx) << 3;          // kstep 1

  f32x4 acc[8][NREP];
#pragma unroll
  for (int m = 0; m < 8; ++m)
#pragma unroll
    for (int n = 0; n < NREP; ++n) acc[m][n] = (f32x4){0.f, 0.f, 0.f, 0.f};

  float4 s0[2 * NREP], s1[2 * NREP];   // two named in-flight B reg sets: B(j) in set[j&1]

#define ISSUE_A(buf, kt)                                                        \
  {                                                                             \
    _Pragma("unroll")                                                           \
    for (int i = 0; i < 4; ++i)                                                 \
      __builtin_amdgcn_global_load_lds((GLV*)(Asrc + (size_t)i * 64 * K + (kt) * 64), \
                                       (LDSV*)&As[buf][(i * 512 + tid) * 8], 16, 0, 0); \
  }
#define ISSUE_B(dst, kt)                                                        \
  {                                                                             \
    const float* g = Bsrc + (kt) * 64;                                          \
    _Pragma("unroll")                                                           \
    for (int i = 0; i < 2 * NREP; ++i) dst[i] = *(const float4*)(g + i * 4);    \
  }
#define CVT_WRITE_B(buf, src)                                                   \
  {                                                                             \
    _Pragma("unroll")                                                           \
    for (int i = 0; i < NREP; ++i)                                              \
      *(uint4*)&Bs[buf][bwrow * 64 + (((bwc + i) ^ (bwrow & 7)) << 3)] =        \
          cvt8u(src[2 * i], src[2 * i + 1]);                                    \
  }
#define BAR()    __builtin_amdgcn_s_barrier()
#define LGKM0()  { asm volatile("s_waitcnt lgkmcnt(0)" ::: "memory");           \
                   __builtin_amdgcn_sched_barrier(0); }
#define MFMA_PH(mb, areg, kh)                                                   \
  {                                                                             \
    __builtin_amdgcn_s_setprio(1);                                              \
    _Pragma("unroll")                                                           \
    for (int m = 0; m < 4; ++m)                                                 \
      _Pragma("unroll")                                                         \
      for (int n = 0; n < NREP; ++n)                                            \
        acc[(mb) * 4 + m][n] =                                                  \
            __builtin_amdgcn_mfma_f32_16x16x32_bf16(areg[m], b8[kh][n],         \
                                                    acc[(mb) * 4 + m][n], 0, 0, 0); \
    __builtin_amdgcn_s_setprio(0);                                              \
  }

  // ---- prologue: tile 0 fully staged; B(1) in regs (set1)
  ISSUE_A(0, 0);
  ISSUE_B(s0, 0);
  asm volatile("s_waitcnt vmcnt(0)" ::: "memory");
  __builtin_amdgcn_sched_barrier(0);
  CVT_WRITE_B(0, s0);
  ISSUE_B(s1, 1);
  asm volatile("s_waitcnt lgkmcnt(0)" ::: "memory");
  __builtin_amdgcn_sched_barrier(0);
  BAR();

  short8 b8[2][NREP];
  for (int t = 0; t < NK; ++t) {
    const int cur = t & 1, nxt = cur ^ 1;
    const bf16* Ab = As[cur];
    const bf16* Bb = Bs[cur];
    short8 aP[4];

    // ---------- phase 0 ----------
    if (t + 1 < NK) {
      ISSUE_A(nxt, t + 1);
      asm volatile("s_waitcnt vmcnt(4)" ::: "memory");   // B(t+1) regs landed
      __builtin_amdgcn_sched_barrier(0);
      if ((t & 1) == 0) { CVT_WRITE_B(nxt, s1); } else { CVT_WRITE_B(nxt, s0); }
    }
#pragma unroll
    for (int m = 0; m < 4; ++m) aP[m] = *(const short8*)&Ab[aro + m * 1024 + ch0];
#pragma unroll
    for (int n = 0; n < NREP; ++n) b8[0][n] = *(const short8*)&Bb[bro + n * 1024 + ch0];
    BAR(); LGKM0();
    MFMA_PH(0, aP, 0);
    BAR();

    // ---------- phase 1 ----------
#pragma unroll
    for (int m = 0; m < 4; ++m) aP[m] = *(const short8*)&Ab[aro + m * 1024 + ch1];
#pragma unroll
    for (int n = 0; n < NREP; ++n) b8[1][n] = *(const short8*)&Bb[bro + n * 1024 + ch1];
    if (t + 2 < NK) {
      if ((t & 1) == 0) { ISSUE_B(s0, t + 2); } else { ISSUE_B(s1, t + 2); }
    }
    BAR(); LGKM0();
    MFMA_PH(0, aP, 1);
    BAR();

    // ---------- phase 2 ----------
#pragma unroll
    for (int m = 0; m < 4; ++m) aP[m] = *(const short8*)&Ab[aro + (m + 4) * 1024 + ch0];
    BAR(); LGKM0();
    MFMA_PH(1, aP, 0);
    BAR();

    // ---------- phase 3 ----------
#pragma unroll
    for (int m = 0; m < 4; ++m) aP[m] = *(const short8*)&Ab[aro + (m + 4) * 1024 + ch1];
    if (t + 2 < NK) {
      if (NREP == 4) asm volatile("s_waitcnt vmcnt(8)" ::: "memory");  // A(t+1) landed
      else           asm volatile("s_waitcnt vmcnt(4)" ::: "memory");
      __builtin_amdgcn_sched_barrier(0);
    } else if (t + 1 < NK) {
      asm volatile("s_waitcnt vmcnt(0)" ::: "memory");
      __builtin_amdgcn_sched_barrier(0);
    }
    BAR(); LGKM0();
    MFMA_PH(1, aP, 1);
    BAR();
  }

  // ---- epilogue
  float bv[NREP];
#pragma unroll
  for (int n = 0; n < NREP; ++n)
    bv[n] = bias[(size_t)e * N + bn * BN + wc * (BN / 4) + n * 16 + fr];

  if (EPI1) {
    bf16* He = Hout + (size_t)e * MPE * N;
#pragma unroll
    for (int m = 0; m < 8; ++m) {
#pragma unroll
      for (int j = 0; j < 4; ++j) {
        const int row = bm * 256 + wr * 128 + m * 16 + fq * 4 + j;
#pragma unroll
        for (int n = 0; n < NREP; ++n) {
          const int col = bn * BN + wc * (BN / 4) + n * 16 + fr;
          float x = acc[m][n][j] + bv[n];
          float g = 0.5f * x * (1.0f + erff(x * 0.70710678118654752f));
          He[(size_t)row * N + col] = __float2bfloat16(g);
        }
      }
    }
  } else {
#pragma unroll
    for (int m = 0; m < 8; ++m) {
#pragma unroll
      for (int j = 0; j < 4; ++j) {
        const int grow = e * MPE + bm * 256 + wr * 128 + m * 16 + fq * 4 + j;
        const int drow = perm[grow];
        float* orow = Oout + (size_t)drow * N;
#pragma unroll
        for (int n = 0; n < NREP; ++n) {
          const int col = bn * BN + wc * (BN / 4) + n * 16 + fr;
          orow[col] = acc[m][n][j] + bv[n];
        }
      }
    }
  }
#undef ISSUE_A
#undef ISSUE_B
#undef CVT_WRITE_B
#undef BAR
#undef LGKM0
#undef MFMA_PH
}

// ---------------- residual + LayerNorm (in place on out) ----------------
__global__ __launch_bounds__(256)
void ln_resid_kernel(float* __restrict__ out, const float* __restrict__ hs,
                     const float* __restrict__ gamma, const float* __restrict__ beta) {
  const int r = blockIdx.x;
  const int t = threadIdx.x;
  float4 o = ((const float4*)(out + (size_t)r * H_DIM))[t];
  float4 h = ((const float4*)(hs  + (size_t)r * H_DIM))[t];
  float v0 = o.x + h.x, v1 = o.y + h.y, v2 = o.z + h.z, v3 = o.w + h.w;
  float s  = v0 + v1 + v2 + v3;
  float sq = v0 * v0 + v1 * v1 + v2 * v2 + v3 * v3;
#pragma unroll
  for (int off = 32; off > 0; off >>= 1) {
    s  += __shfl_down(s, off);
    sq += __shfl_down(sq, off);
  }
  __shared__ float ss[4], ssq[4];
  const int wv = t >> 6;
  if ((t & 63) == 0) { ss[wv] = s; ssq[wv] = sq; }
  __syncthreads();
  s  = ss[0] + ss[1] + ss[2] + ss[3];
  sq = ssq[0] + ssq[1] + ssq[2] + ssq[3];
  const float mu  = s * (1.0f / (float)H_DIM);
  const float var = sq * (1.0f / (float)H_DIM) - mu * mu;
  const float rs  = rsqrtf(var + 1e-12f);
  float4 g = ((const float4*)gamma)[t];
  float4 b = ((const float4*)beta)[t];
  float4 rr;
  rr.x = (v0 - mu) * rs * g.x + b.x;
  rr.y = (v1 - mu) * rs * g.y + b.y;
  rr.z = (v2 - mu) * rs * g.z + b.z;
  rr.w = (v3 - mu) * rs * g.w + b.w;
  ((float4*)(out + (size_t)r * H_DIM))[t] = rr;
}

extern "C" void kernel_launch(void* const* d_in, const int* in_sizes, int n_in,
                              void* d_out, int out_size, void* d_ws, size_t ws_size,
                              hipStream_t stream) {
  const float* hs    = (const float*)d_in[0];
  const int*   perm  = (const int*)d_in[1];
  const float* w1    = (const float*)d_in[2];
  const float* b1    = (const float*)d_in[3];
  const float* w2    = (const float*)d_in[4];
  const float* b2    = (const float*)d_in[5];
  const float* gamma = (const float*)d_in[6];
  const float* beta  = (const float*)d_in[7];
  float* out = (float*)d_out;

  bf16* xp   = (bf16*)d_ws;                                              // 16 MB
  bf16* hbuf = (bf16*)((char*)d_ws + (size_t)T_NUM * H_DIM * sizeof(bf16)); // 64 MB

  gather_cast_kernel<<<T_NUM, 256, 0, stream>>>(hs, perm, (uint32_t*)xp);

  // GEMM1: BM=256, BN=256 -> nwg = 2 * 16 * 16 = 512
  moe_gemm_kernel<true, 256, I_DIM, H_DIM, 4><<<512, 512, 0, stream>>>(xp, w1, b1, hbuf, nullptr, nullptr);

  // GEMM2: BM=256, BN=128 -> nwg = 2 * 8 * 16 = 256
  moe_gemm_kernel<false, 128, H_DIM, I_DIM, 3><<<256, 512, 0, stream>>>(hbuf, w2, b2, nullptr, out, perm);

  ln_resid_kernel<<<T_NUM, 256, 0, stream>>>(out, hs, gamma, beta);
}

// Round 7
// 427.080 us; speedup vs baseline: 1.2069x; 1.2069x over previous
//
#include <hip/hip_runtime.h>
#include <hip/hip_bf16.h>
#include <stdint.h>

#define E_NUM 16
#define T_NUM 8192
#define H_DIM 1024
#define I_DIM 4096
#define MPE   512   // tokens per expert

typedef __attribute__((ext_vector_type(8))) short short8;
typedef __attribute__((ext_vector_type(4))) float f32x4;
using bf16 = __hip_bfloat16;

typedef const __attribute__((address_space(1))) void GLV;
typedef __attribute__((address_space(3))) void LDSV;

__device__ __forceinline__ uint32_t pack2_bf16(float a, float b) {
  union { float f; uint32_t u; } ua, ub;
  ua.f = a; ub.f = b;
  uint32_t x = ua.u + (0x7FFFu + ((ua.u >> 16) & 1u));
  uint32_t y = ub.u + (0x7FFFu + ((ub.u >> 16) & 1u));
  return (x >> 16) | (y & 0xFFFF0000u);
}

// 8 f32 (two f32x4) -> short8 of bf16 (RNE, v_cvt_pk_bf16_f32)
__device__ __forceinline__ short8 cvt8(f32x4 a, f32x4 b) {
  union { short8 s; __hip_bfloat162 h[4]; } r;
  r.h[0] = __float22bfloat162_rn({a[0], a[1]});
  r.h[1] = __float22bfloat162_rn({a[2], a[3]});
  r.h[2] = __float22bfloat162_rn({b[0], b[1]});
  r.h[3] = __float22bfloat162_rn({b[2], b[3]});
  return r.s;
}

// ---------------- gather + cast: xp[r] = bf16(hs[perm[r]]) ----------------
__global__ __launch_bounds__(256)
void gather_cast_kernel(const float* __restrict__ hs, const int* __restrict__ perm,
                        uint32_t* __restrict__ xp) {
  const int r = blockIdx.x;
  const int t = threadIdx.x;
  const int src = perm[r];
  float4 v = ((const float4*)(hs + (size_t)src * H_DIM))[t];
  uint2 o;
  o.x = pack2_bf16(v.x, v.y);
  o.y = pack2_bf16(v.z, v.w);
  ((uint2*)(xp + (size_t)r * (H_DIM / 2)))[t] = o;
}

// ---------------- grouped GEMM, m97-simple structure ----------------
// C = A(bf16,[E][512][K]) * B(f32,[E][N][K])^T.  128x128 tile, BK=32.
// 256 thr = 4 waves (2x2), per-wave 64x64 (4x4 frags), acc 64 VGPR.
// BOTH operands staged global_load_lds-direct (no reg round-trip, no ds_write):
//   A: [64 lds-rows][64 bf16] row-pair-packed (lds row p = real rows p and p+64,
//      granule g: g>>2 = half, g&3 = k-chunk), phys slot = g ^ (p&7) via
//      pre-swizzled source -> 2-way bank aliasing only (free, m136).
//   B: [128 rows][32 f32] (128-B rows), phys granule = g ^ (row&7), the
//      R4-validated geometry; cvt_pk f32->bf16 on the READ side.
// LDS 48 KB dbuf -> 3 blocks/CU (12 waves): block-level latency overlap (m114)
// with the plain stage(t+1) / compute(t) / __syncthreads() loop (m97).
template<bool EPI1, int N, int K, int LOG_NBN>
__global__ __launch_bounds__(256, 3)
void moe_gemm_kernel(const bf16* __restrict__ A, const float* __restrict__ Bw,
                     const float* __restrict__ bias, bf16* __restrict__ Hout,
                     float* __restrict__ Oout, const int* __restrict__ perm) {
  constexpr int NK = K / 32;
  __shared__ bf16  As[2][64 * 64];    // 8 KB each
  __shared__ float Bs[2][128 * 32];   // 16 KB each

  // bijective chunked XCD swizzle (m204); nwg % 8 == 0
  const int nwg = gridDim.x, qx = nwg >> 3, orig = blockIdx.x;
  const int wg = (orig & 7) * qx + (orig >> 3);
  const int bm = wg & 3;
  const int bn = (wg >> 2) & ((1 << LOG_NBN) - 1);
  const int e  = wg >> (2 + LOG_NBN);

  const int tid = threadIdx.x;
  const int l = tid & 63;
  const int w = tid >> 6;
  const int wr = w >> 1, wc = w & 1;       // 2 M-waves x 2 N-waves
  const int fr = l & 15, fq = l >> 4;
  const int rx = fr & 7;

  const bf16*  Ae = A  + ((size_t)e * MPE + (size_t)bm * 128) * K;
  const float* Be = Bw + ((size_t)e * N + (size_t)bn * 128) * K;

  // A staging: granule idx = i*256+tid (i=0,1); lds row p = 32*i + (tid>>3),
  // slot s = tid&7, logical g = s ^ (p&7) = s ^ ((tid>>3)&7) (32*i == 0 mod 8).
  // real row = p + 64*(g>>2), k-chunk = (g&3)*8 elems.
  const int ap = tid >> 3;
  const int ag = (tid & 7) ^ (ap & 7);
  const bf16* Asrc0 = Ae + (size_t)(ap      + 64 * (ag >> 2)) * K + (ag & 3) * 8;
  const bf16* Asrc1 = Ae + (size_t)(ap + 32 + 64 * (ag >> 2)) * K + (ag & 3) * 8;

  // B staging: granule idx = i*256+tid (i=0..3); row = 32*i + (tid>>3),
  // slot = tid&7, logical g = slot ^ (row&7) = slot ^ ((tid>>3)&7).
  const float* Bsrc = Be + (size_t)(tid >> 3) * K + ((tid & 7) ^ ((tid >> 3) & 7)) * 4;

  // fragment read offsets
  // A frag m: lds row p = m*16 + fr, slot = (wr*4+fq) ^ (fr&7) (16 == 0 mod 8)
  const int aso = ((wr * 4 + fq) ^ rx) * 8;                // elem offset of slot
  // B frag n: row = wc*64 + n*16 + fr; phys granules (2fq)^rx, (2fq+1)^rx
  const int bro = 0;  // base handled inline
  const int bp0 = ((2 * fq)     ^ rx) * 4;
  const int bp1 = ((2 * fq + 1) ^ rx) * 4;
  (void)bro;

#define STAGE(buf, kt)                                                            \
  {                                                                               \
    __builtin_amdgcn_global_load_lds((GLV*)(Asrc0 + (kt) * 32),                   \
                                     (LDSV*)&As[buf][tid * 8], 16, 0, 0);         \
    __builtin_amdgcn_global_load_lds((GLV*)(Asrc1 + (kt) * 32),                   \
                                     (LDSV*)&As[buf][(256 + tid) * 8], 16, 0, 0); \
    _Pragma("unroll")                                                             \
    for (int i = 0; i < 4; ++i)                                                   \
      __builtin_amdgcn_global_load_lds((GLV*)(Bsrc + (size_t)i * 32 * K + (kt) * 32), \
                                       (LDSV*)&Bs[buf][(i * 256 + tid) * 4], 16, 0, 0); \
  }

  f32x4 acc[4][4];
#pragma unroll
  for (int m = 0; m < 4; ++m)
#pragma unroll
    for (int n = 0; n < 4; ++n) acc[m][n] = (f32x4){0.f, 0.f, 0.f, 0.f};

  // ---- prologue
  STAGE(0, 0);
  __syncthreads();

  for (int t = 0; t < NK; ++t) {
    const int cur = t & 1, nxt = cur ^ 1;
    if (t + 1 < NK) STAGE(nxt, t + 1);

    short8 a8[4], b8[4];
#pragma unroll
    for (int m = 0; m < 4; ++m)
      a8[m] = *(const short8*)&As[cur][(m * 16 + fr) * 64 + aso];
#pragma unroll
    for (int n = 0; n < 4; ++n) {
      const int col = wc * 64 + n * 16 + fr;
      const f32x4 x0 = *(const f32x4*)&Bs[cur][col * 32 + bp0];
      const f32x4 x1 = *(const f32x4*)&Bs[cur][col * 32 + bp1];
      b8[n] = cvt8(x0, x1);
    }
#pragma unroll
    for (int m = 0; m < 4; ++m)
#pragma unroll
      for (int n = 0; n < 4; ++n)
        acc[m][n] = __builtin_amdgcn_mfma_f32_16x16x32_bf16(a8[m], b8[n], acc[m][n], 0, 0, 0);

    __syncthreads();
  }
#undef STAGE

  // ---- epilogue (R2-validated indexing)
  float bv[4];
#pragma unroll
  for (int n = 0; n < 4; ++n)
    bv[n] = bias[(size_t)e * N + bn * 128 + wc * 64 + n * 16 + fr];

  if (EPI1) {
    bf16* He = Hout + (size_t)e * MPE * N;
#pragma unroll
    for (int m = 0; m < 4; ++m) {
#pragma unroll
      for (int j = 0; j < 4; ++j) {
        const int row = bm * 128 + wr * 64 + m * 16 + fq * 4 + j;
#pragma unroll
        for (int n = 0; n < 4; ++n) {
          const int col = bn * 128 + wc * 64 + n * 16 + fr;
          float x = acc[m][n][j] + bv[n];
          float g = 0.5f * x * (1.0f + erff(x * 0.70710678118654752f));
          He[(size_t)row * N + col] = __float2bfloat16(g);
        }
      }
    }
  } else {
#pragma unroll
    for (int m = 0; m < 4; ++m) {
#pragma unroll
      for (int j = 0; j < 4; ++j) {
        const int grow = e * MPE + bm * 128 + wr * 64 + m * 16 + fq * 4 + j;
        const int drow = perm[grow];
        float* orow = Oout + (size_t)drow * N;
#pragma unroll
        for (int n = 0; n < 4; ++n) {
          const int col = bn * 128 + wc * 64 + n * 16 + fr;
          orow[col] = acc[m][n][j] + bv[n];
        }
      }
    }
  }
}

// ---------------- residual + LayerNorm (in place on out) ----------------
__global__ __launch_bounds__(256)
void ln_resid_kernel(float* __restrict__ out, const float* __restrict__ hs,
                     const float* __restrict__ gamma, const float* __restrict__ beta) {
  const int r = blockIdx.x;
  const int t = threadIdx.x;
  float4 o = ((const float4*)(out + (size_t)r * H_DIM))[t];
  float4 h = ((const float4*)(hs  + (size_t)r * H_DIM))[t];
  float v0 = o.x + h.x, v1 = o.y + h.y, v2 = o.z + h.z, v3 = o.w + h.w;
  float s  = v0 + v1 + v2 + v3;
  float sq = v0 * v0 + v1 * v1 + v2 * v2 + v3 * v3;
#pragma unroll
  for (int off = 32; off > 0; off >>= 1) {
    s  += __shfl_down(s, off);
    sq += __shfl_down(sq, off);
  }
  __shared__ float ss[4], ssq[4];
  const int wv = t >> 6;
  if ((t & 63) == 0) { ss[wv] = s; ssq[wv] = sq; }
  __syncthreads();
  s  = ss[0] + ss[1] + ss[2] + ss[3];
  sq = ssq[0] + ssq[1] + ssq[2] + ssq[3];
  const float mu  = s * (1.0f / (float)H_DIM);
  const float var = sq * (1.0f / (float)H_DIM) - mu * mu;
  const float rs  = rsqrtf(var + 1e-12f);
  float4 g = ((const float4*)gamma)[t];
  float4 b = ((const float4*)beta)[t];
  float4 rr;
  rr.x = (v0 - mu) * rs * g.x + b.x;
  rr.y = (v1 - mu) * rs * g.y + b.y;
  rr.z = (v2 - mu) * rs * g.z + b.z;
  rr.w = (v3 - mu) * rs * g.w + b.w;
  ((float4*)(out + (size_t)r * H_DIM))[t] = rr;
}

extern "C" void kernel_launch(void* const* d_in, const int* in_sizes, int n_in,
                              void* d_out, int out_size, void* d_ws, size_t ws_size,
                              hipStream_t stream) {
  const float* hs    = (const float*)d_in[0];
  const int*   perm  = (const int*)d_in[1];
  const float* w1    = (const float*)d_in[2];
  const float* b1    = (const float*)d_in[3];
  const float* w2    = (const float*)d_in[4];
  const float* b2    = (const float*)d_in[5];
  const float* gamma = (const float*)d_in[6];
  const float* beta  = (const float*)d_in[7];
  float* out = (float*)d_out;

  bf16* xp   = (bf16*)d_ws;                                                  // 16 MB
  bf16* hbuf = (bf16*)((char*)d_ws + (size_t)T_NUM * H_DIM * sizeof(bf16));  // 64 MB

  gather_cast_kernel<<<T_NUM, 256, 0, stream>>>(hs, perm, (uint32_t*)xp);

  // GEMM1: 4 bm x 32 bn x 16 e = 2048 blocks
  moe_gemm_kernel<true, I_DIM, H_DIM, 5><<<2048, 256, 0, stream>>>(xp, w1, b1, hbuf, nullptr, nullptr);

  // GEMM2: 4 bm x 8 bn x 16 e = 512 blocks
  moe_gemm_kernel<false, H_DIM, I_DIM, 3><<<512, 256, 0, stream>>>(hbuf, w2, b2, nullptr, out, perm);

  ln_resid_kernel<<<T_NUM, 256, 0, stream>>>(out, hs, gamma, beta);
}

// Round 8
// 328.511 us; speedup vs baseline: 1.5691x; 1.3000x over previous
//
#include <hip/hip_runtime.h>
#include <hip/hip_bf16.h>
#include <stdint.h>

#define E_NUM 16
#define T_NUM 8192
#define H_DIM 1024
#define I_DIM 4096
#define MPE   512   // tokens per expert

typedef __attribute__((ext_vector_type(8))) short short8;
typedef __attribute__((ext_vector_type(4))) float f32x4;
using bf16 = __hip_bfloat16;

typedef const __attribute__((address_space(1))) void GLV;
typedef __attribute__((address_space(3))) void LDSV;

__device__ __forceinline__ uint32_t pack2_bf16(float a, float b) {
  union { float f; uint32_t u; } ua, ub;
  ua.f = a; ub.f = b;
  uint32_t x = ua.u + (0x7FFFu + ((ua.u >> 16) & 1u));
  uint32_t y = ub.u + (0x7FFFu + ((ub.u >> 16) & 1u));
  return (x >> 16) | (y & 0xFFFF0000u);
}

// 8 f32 (two f32x4) -> short8 of bf16 (RNE, v_cvt_pk_bf16_f32)
__device__ __forceinline__ short8 cvt8(f32x4 a, f32x4 b) {
  union { short8 s; __hip_bfloat162 h[4]; } r;
  r.h[0] = __float22bfloat162_rn({a[0], a[1]});
  r.h[1] = __float22bfloat162_rn({a[2], a[3]});
  r.h[2] = __float22bfloat162_rn({b[0], b[1]});
  r.h[3] = __float22bfloat162_rn({b[2], b[3]});
  return r.s;
}

// ---------------- gather + cast: xp[r] = bf16(hs[perm[r]]) ----------------
__global__ __launch_bounds__(256)
void gather_cast_kernel(const float* __restrict__ hs, const int* __restrict__ perm,
                        uint32_t* __restrict__ xp) {
  const int r = blockIdx.x;
  const int t = threadIdx.x;
  const int src = perm[r];
  float4 v = ((const float4*)(hs + (size_t)src * H_DIM))[t];
  uint2 o;
  o.x = pack2_bf16(v.x, v.y);
  o.y = pack2_bf16(v.z, v.w);
  ((uint2*)(xp + (size_t)r * (H_DIM / 2)))[t] = o;
}

// ---------------- grouped GEMM, BM=512 (weights fetched ONCE) ----------------
// C = A(bf16,[E][512][KFULL]) * B(f32,[E][N][KFULL])^T over K window [K0,K0+KLEN).
// BM=512 (whole expert), BN=128, BK=32.  1024 thr = 16 waves (8M x 2N);
// per-wave 64x64 (4x4 frags), acc 64 VGPR; __launch_bounds__(1024,4) caps 128.
// LDS dbuf 96 KB (1 block/CU):
//   A: 512x32 bf16 row-pair-packed: lds-row p(0..255) holds real rows p & p+256;
//      granule g at slot s = g^(p&7); staged via glds w/ pre-swizzled source.
//   B: [128][32] f32 (128-B rows), granule s = g^(row&7) (R7-validated);
//      cvt_pk f32->bf16 on the read side.
// EPI=1: Hout[e][row][col] = bf16(gelu(acc + b1))
// EPI=0: Pout[ks][e*512+row][col] = acc (f32 partial; bias+reduce in LN kernel)
template<int EPI, int KSPLIT, int N, int KFULL, int KLEN, int LOG_NBN>
__global__ __launch_bounds__(1024, 4)
void moe_gemm_kernel(const bf16* __restrict__ A, const float* __restrict__ Bw,
                     const float* __restrict__ bias, bf16* __restrict__ Hout,
                     float* __restrict__ Pout) {
  constexpr int NK = KLEN / 32;
  __shared__ bf16  As[2][512 * 32];   // 32 KB each
  __shared__ float Bs[2][128 * 32];   // 16 KB each

  // bijective chunked XCD swizzle (m204); nwg % 8 == 0
  const int nwg = gridDim.x, qx = nwg >> 3, orig = blockIdx.x;
  const int wg = (orig & 7) * qx + (orig >> 3);
  const int bn   = wg & ((1 << LOG_NBN) - 1);
  const int rest = wg >> LOG_NBN;
  const int ks = (KSPLIT == 2) ? (rest & 1) : 0;
  const int e  = (KSPLIT == 2) ? (rest >> 1) : rest;
  const int K0 = ks * KLEN;

  const int tid = threadIdx.x;
  const int l = tid & 63;
  const int w = tid >> 6;                  // 0..15
  const int wr = w >> 1, wc = w & 1;       // 8 M-waves x 2 N-waves
  const int fr = l & 15, fq = l >> 4;
  const int rx = fr & 7;

  const bf16*  Ae = A  + (size_t)e * MPE * KFULL + K0;
  const float* Be = Bw + ((size_t)e * N + (size_t)bn * 128) * KFULL + K0;

  // A staging: granule j = i*1024+tid (i=0,1); lds-row p = i*128 + (tid>>3),
  // slot s = tid&7, logical g = s ^ (p&7); real row = p + 256*(g>>2),
  // k-chunk = (g&3)*8 elems.  (i*128 mod 8 == 0, so swizzle const over i.)
  const int apq = tid >> 3;
  const int ag  = (tid & 7) ^ (apq & 7);
  const bf16* Asrc0 = Ae + (size_t)(apq       + 256 * (ag >> 2)) * KFULL + (ag & 3) * 8;
  const bf16* Asrc1 = Ae + (size_t)(apq + 128 + 256 * (ag >> 2)) * KFULL + (ag & 3) * 8;

  // B staging: granule j = tid; row = tid>>3 (0..127), slot = tid&7,
  // logical g = slot ^ (row&7), source col offset g*4 f32 (R7-validated).
  const float* Bsrc = Be + (size_t)(tid >> 3) * KFULL + ((tid & 7) ^ ((tid >> 3) & 7)) * 4;

  // fragment read offsets
  // A frag m: real row r = wr*64+m*16+fr -> lds-row p = (wr&3)*64+m*16+fr,
  //           slot = (((wr>>2)<<2)|fq) ^ rx   (elem addr = p*64 + slot*8)
  const int aso = (((((wr >> 2) << 2)) | fq) ^ rx) * 8;
  // B frag n: row = wc*64+n*16+fr; granules (2fq)^rx and (2fq+1)^rx
  const int bp0 = (((fq << 1))     ^ rx) * 4;
  const int bp1 = (((fq << 1) | 1) ^ rx) * 4;

#define STAGE(buf, kt)                                                              \
  {                                                                                 \
    __builtin_amdgcn_global_load_lds((GLV*)(Asrc0 + (kt) * 32),                     \
                                     (LDSV*)&As[buf][tid * 8], 16, 0, 0);           \
    __builtin_amdgcn_global_load_lds((GLV*)(Asrc1 + (kt) * 32),                     \
                                     (LDSV*)&As[buf][(1024 + tid) * 8], 16, 0, 0);  \
    __builtin_amdgcn_global_load_lds((GLV*)(Bsrc + (kt) * 32),                      \
                                     (LDSV*)&Bs[buf][tid * 4], 16, 0, 0);           \
  }

  f32x4 acc[4][4];
#pragma unroll
  for (int m = 0; m < 4; ++m)
#pragma unroll
    for (int n = 0; n < 4; ++n) acc[m][n] = (f32x4){0.f, 0.f, 0.f, 0.f};

  // ---- prologue
  STAGE(0, 0);
  __syncthreads();

  for (int t = 0; t < NK; ++t) {
    const int cur = t & 1, nxt = cur ^ 1;
    if (t + 1 < NK) STAGE(nxt, t + 1);

    short8 a8[4];
#pragma unroll
    for (int m = 0; m < 4; ++m)
      a8[m] = *(const short8*)&As[cur][((wr & 3) * 64 + m * 16 + fr) * 64 + aso];

#pragma unroll
    for (int n = 0; n < 4; ++n) {
      const int col = wc * 64 + n * 16 + fr;
      const f32x4 x0 = *(const f32x4*)&Bs[cur][col * 32 + bp0];
      const f32x4 x1 = *(const f32x4*)&Bs[cur][col * 32 + bp1];
      const short8 b8 = cvt8(x0, x1);
#pragma unroll
      for (int m = 0; m < 4; ++m)
        acc[m][n] = __builtin_amdgcn_mfma_f32_16x16x32_bf16(a8[m], b8, acc[m][n], 0, 0, 0);
    }

    __syncthreads();
  }
#undef STAGE

  // ---- epilogue
  if (EPI == 1) {
    float bv[4];
#pragma unroll
    for (int n = 0; n < 4; ++n)
      bv[n] = bias[(size_t)e * N + bn * 128 + wc * 64 + n * 16 + fr];
    bf16* He = Hout + (size_t)e * MPE * N;
#pragma unroll
    for (int m = 0; m < 4; ++m) {
#pragma unroll
      for (int j = 0; j < 4; ++j) {
        const int row = wr * 64 + m * 16 + fq * 4 + j;
#pragma unroll
        for (int n = 0; n < 4; ++n) {
          const int col = bn * 128 + wc * 64 + n * 16 + fr;
          float x = acc[m][n][j] + bv[n];
          float g = 0.5f * x * (1.0f + erff(x * 0.70710678118654752f));
          He[(size_t)row * N + col] = __float2bfloat16(g);
        }
      }
    }
  } else {
    float* Pd = Pout + (size_t)ks * T_NUM * H_DIM + (size_t)e * MPE * N;
#pragma unroll
    for (int m = 0; m < 4; ++m) {
#pragma unroll
      for (int j = 0; j < 4; ++j) {
        const int row = wr * 64 + m * 16 + fq * 4 + j;
#pragma unroll
        for (int n = 0; n < 4; ++n) {
          const int col = bn * 128 + wc * 64 + n * 16 + fr;
          Pd[(size_t)row * N + col] = acc[m][n][j];
        }
      }
    }
  }
}

// -------- reduce partials + bias + residual + LayerNorm + scatter ----------
// out[perm[r]] = LN(p0[r] (+ p1[r]) + b2[e] + hs[perm[r]])
__global__ __launch_bounds__(256)
void ln_resid2_kernel(float* __restrict__ out, const float* __restrict__ hs,
                      const float* __restrict__ p0, const float* __restrict__ p1,
                      const float* __restrict__ b2, const float* __restrict__ gamma,
                      const float* __restrict__ beta, const int* __restrict__ perm,
                      const int two) {
  const int r = blockIdx.x;
  const int t = threadIdx.x;
  const int e = r >> 9;
  const int drow = perm[r];
  float4 a = ((const float4*)(p0 + (size_t)r * H_DIM))[t];
  if (two) {
    float4 b = ((const float4*)(p1 + (size_t)r * H_DIM))[t];
    a.x += b.x; a.y += b.y; a.z += b.z; a.w += b.w;
  }
  float4 bb = ((const float4*)(b2 + (size_t)e * H_DIM))[t];
  float4 h  = ((const float4*)(hs + (size_t)drow * H_DIM))[t];
  float v0 = a.x + bb.x + h.x, v1 = a.y + bb.y + h.y;
  float v2 = a.z + bb.z + h.z, v3 = a.w + bb.w + h.w;
  float s  = v0 + v1 + v2 + v3;
  float sq = v0 * v0 + v1 * v1 + v2 * v2 + v3 * v3;
#pragma unroll
  for (int off = 32; off > 0; off >>= 1) {
    s  += __shfl_down(s, off);
    sq += __shfl_down(sq, off);
  }
  __shared__ float ss[4], ssq[4];
  const int wv = t >> 6;
  if ((t & 63) == 0) { ss[wv] = s; ssq[wv] = sq; }
  __syncthreads();
  s  = ss[0] + ss[1] + ss[2] + ss[3];
  sq = ssq[0] + ssq[1] + ssq[2] + ssq[3];
  const float mu  = s * (1.0f / (float)H_DIM);
  const float var = sq * (1.0f / (float)H_DIM) - mu * mu;
  const float rs  = rsqrtf(var + 1e-12f);
  float4 g = ((const float4*)gamma)[t];
  float4 b = ((const float4*)beta)[t];
  float4 rr;
  rr.x = (v0 - mu) * rs * g.x + b.x;
  rr.y = (v1 - mu) * rs * g.y + b.y;
  rr.z = (v2 - mu) * rs * g.z + b.z;
  rr.w = (v3 - mu) * rs * g.w + b.w;
  ((float4*)(out + (size_t)drow * H_DIM))[t] = rr;
}

extern "C" void kernel_launch(void* const* d_in, const int* in_sizes, int n_in,
                              void* d_out, int out_size, void* d_ws, size_t ws_size,
                              hipStream_t stream) {
  const float* hs    = (const float*)d_in[0];
  const int*   perm  = (const int*)d_in[1];
  const float* w1    = (const float*)d_in[2];
  const float* b1    = (const float*)d_in[3];
  const float* w2    = (const float*)d_in[4];
  const float* b2    = (const float*)d_in[5];
  const float* gamma = (const float*)d_in[6];
  const float* beta  = (const float*)d_in[7];
  float* out = (float*)d_out;

  const size_t xp_b   = (size_t)T_NUM * H_DIM * sizeof(bf16);   // 16 MB
  const size_t hbuf_b = (size_t)T_NUM * I_DIM * sizeof(bf16);   // 64 MB
  const size_t part_b = (size_t)T_NUM * H_DIM * sizeof(float);  // 32 MB each

  bf16*  xp   = (bf16*)d_ws;
  bf16*  hbuf = (bf16*)((char*)d_ws + xp_b);
  float* pbuf = (float*)((char*)d_ws + xp_b + hbuf_b);

  gather_cast_kernel<<<T_NUM, 256, 0, stream>>>(hs, perm, (uint32_t*)xp);

  // GEMM1: BM=512 -> w1 fetched exactly once. grid = 32 bn x 16 e = 512
  moe_gemm_kernel<1, 1, I_DIM, H_DIM, H_DIM, 5>
      <<<512, 1024, 0, stream>>>(xp, w1, b1, hbuf, nullptr);

  if (ws_size >= xp_b + hbuf_b + 2 * part_b) {
    // GEMM2 split-K=2: w2 fetched once; grid = 8 bn x 2 ks x 16 e = 256
    moe_gemm_kernel<0, 2, H_DIM, I_DIM, I_DIM / 2, 3>
        <<<256, 1024, 0, stream>>>(hbuf, w2, nullptr, nullptr, pbuf);
    ln_resid2_kernel<<<T_NUM, 256, 0, stream>>>(out, hs, pbuf, pbuf + (size_t)T_NUM * H_DIM,
                                                b2, gamma, beta, perm, 1);
  } else {
    // fallback: single-pass K, grid = 8 bn x 16 e = 128 (half GPU)
    moe_gemm_kernel<0, 1, H_DIM, I_DIM, I_DIM, 3>
        <<<128, 1024, 0, stream>>>(hbuf, w2, nullptr, nullptr, pbuf);
    ln_resid2_kernel<<<T_NUM, 256, 0, stream>>>(out, hs, pbuf, nullptr,
                                                b2, gamma, beta, perm, 0);
  }
}